// Round 3
// baseline (137.683 us; speedup 1.0000x reference)
//
#include <hip/hip_runtime.h>

// ToChoices: out[b,h,w,s,c] = (shuffle_indices[b,s] ? reals : fakes)[b,h,w,c]
// Shapes: reals/fakes (64,256,256,3) f32, shuffle_indices (64,2) int,
// out (64,256,256,2,3) f32.
//
// Memory-bound interleave. One thread per 4-PIXEL group:
//   - reads 12 floats (48 B) from each selected source: 3x float4, 16B-aligned
//     (byte offset = pb*12, pb % 4 == 0 -> multiple of 48)
//   - writes 24 floats (96 B): 6x nontemporal 16B stores (output is
//     write-once, never re-read -> don't pollute L2; loads stay cached so
//     the s0==s1 case dedups in L2).
//
// Note: __builtin_nontemporal_store needs a native clang vector type, not
// HIP's float4 class -> use ext_vector_type(4).

typedef float f32x4 __attribute__((ext_vector_type(4)));

#define BB 64
#define HH 256
#define WW 256
#define HW (HH * WW)            // 65536 pixels per image
#define GRPS_PER_B (HW / 4)     // 16384 4-pixel groups per image

__global__ __launch_bounds__(256) void tochoices_kernel(
    const float* __restrict__ reals,
    const float* __restrict__ fakes,
    const int* __restrict__ idx,
    float* __restrict__ out)
{
    int t  = blockIdx.x * blockDim.x + threadIdx.x;  // group index, < 1,048,576
    int b  = t >> 14;                                // t / GRPS_PER_B
    int rp = t & (GRPS_PER_B - 1);

    // choice slot 0 = fakes, 1 = reals
    const float* s0 = idx[b * 2 + 0] ? reals : fakes;
    const float* s1 = idx[b * 2 + 1] ? reals : fakes;

    long pb = (long)b * HW + (long)rp * 4;           // first pixel of the group

    const f32x4* p0 = (const f32x4*)(s0 + pb * 3);   // 12 floats = 3 x 16B
    const f32x4* p1 = (const f32x4*)(s1 + pb * 3);
    f32x4 A0 = p0[0], A1 = p0[1], A2 = p0[2];        // a0..a11 (slot 0 source)
    f32x4 B0 = p1[0], B1 = p1[1], B2 = p1[2];        // b0..b11 (slot 1 source)

    // Per 4 pixels the output is: [a0 a1 a2][b0 b1 b2][a3 a4 a5][b3 b4 b5]
    //                             [a6 a7 a8][b6 b7 b8][a9 a10 a11][b9 b10 b11]
    f32x4* o = (f32x4*)(out + (long)b * (HW * 6) + (long)rp * 24);
    f32x4 v;
    v.x = A0.x; v.y = A0.y; v.z = A0.z; v.w = B0.x;
    __builtin_nontemporal_store(v, o + 0);
    v.x = B0.y; v.y = B0.z; v.z = A0.w; v.w = A1.x;
    __builtin_nontemporal_store(v, o + 1);
    v.x = A1.y; v.y = B0.w; v.z = B1.x; v.w = B1.y;
    __builtin_nontemporal_store(v, o + 2);
    v.x = A1.z; v.y = A1.w; v.z = A2.x; v.w = B1.z;
    __builtin_nontemporal_store(v, o + 3);
    v.x = B1.w; v.y = B2.x; v.z = A2.y; v.w = A2.z;
    __builtin_nontemporal_store(v, o + 4);
    v.x = A2.w; v.y = B2.y; v.z = B2.z; v.w = B2.w;
    __builtin_nontemporal_store(v, o + 5);
}

extern "C" void kernel_launch(void* const* d_in, const int* in_sizes, int n_in,
                              void* d_out, int out_size, void* d_ws, size_t ws_size,
                              hipStream_t stream) {
    const float* reals = (const float*)d_in[0];
    const float* fakes = (const float*)d_in[1];
    const int*   idx   = (const int*)d_in[2];
    float* out = (float*)d_out;

    const int total_groups = BB * GRPS_PER_B;        // 1,048,576
    const int block = 256;
    const int grid = total_groups / block;           // 4096
    tochoices_kernel<<<grid, block, 0, stream>>>(reals, fakes, idx, out);
}

// Round 4
// 40.702 us; speedup vs baseline: 3.3827x; 3.3827x over previous
//
#include <hip/hip_runtime.h>

// ToChoices: out[b,h,w,s,c] = (shuffle_indices[b,s] ? reals : fakes)[b,h,w,c]
// Shapes: reals/fakes (64,256,256,3) f32, shuffle_indices (64,2) int,
// out (64,256,256,2,3) f32.
//
// Memory-bound interleave. One thread per 4-PIXEL group:
//   - reads 12 floats (48 B) from each needed source: 3x float4, 16B-aligned
//     (byte offset = pb*12, pb % 4 == 0 -> multiple of 48)
//   - when both slots pick the same source (50% of batches), load ONCE and
//     reuse registers -> cuts L1/L2 read request traffic by ~25% on average
//   - writes 24 floats (96 B): 6x plain (cached) 16B stores. L2 merges the
//     per-instruction strided partials into full lines. (R3 lesson:
//     nontemporal stores defeat that merge -> 4x regression. Never again.)
//
// Block = 256 threads x 4 pixels = 1024 pixels, and HW=65536 is divisible by
// 1024 -> every block lies in ONE batch image -> idx branch is wave-uniform.

typedef float f32x4 __attribute__((ext_vector_type(4)));

#define BB 64
#define HH 256
#define WW 256
#define HW (HH * WW)            // 65536 pixels per image
#define GRPS_PER_B (HW / 4)     // 16384 4-pixel groups per image

__global__ __launch_bounds__(256) void tochoices_kernel(
    const float* __restrict__ reals,
    const float* __restrict__ fakes,
    const int* __restrict__ idx,
    float* __restrict__ out)
{
    int t  = blockIdx.x * blockDim.x + threadIdx.x;  // group index, < 1,048,576
    int b  = t >> 14;                                // t / GRPS_PER_B
    int rp = t & (GRPS_PER_B - 1);

    int i0 = idx[b * 2 + 0];     // choice slot 0: 0 = fakes, 1 = reals
    int i1 = idx[b * 2 + 1];

    long pb = (long)b * HW + (long)rp * 4;           // first pixel of the group

    const float* s0 = i0 ? reals : fakes;
    const f32x4* p0 = (const f32x4*)(s0 + pb * 3);   // 12 floats = 3 x 16B
    f32x4 A0 = p0[0], A1 = p0[1], A2 = p0[2];        // slot-0 source pixels

    f32x4 B0, B1, B2;                                // slot-1 source pixels
    if (i1 == i0) {                                  // block-uniform branch
        B0 = A0; B1 = A1; B2 = A2;
    } else {
        const float* s1 = i1 ? reals : fakes;
        const f32x4* p1 = (const f32x4*)(s1 + pb * 3);
        B0 = p1[0]; B1 = p1[1]; B2 = p1[2];
    }

    // Per 4 pixels the output is: [a0 a1 a2][b0 b1 b2][a3 a4 a5][b3 b4 b5]
    //                             [a6 a7 a8][b6 b7 b8][a9 a10 a11][b9 b10 b11]
    f32x4* o = (f32x4*)(out + (long)b * (HW * 6) + (long)rp * 24);
    f32x4 v;
    v.x = A0.x; v.y = A0.y; v.z = A0.z; v.w = B0.x;  o[0] = v;
    v.x = B0.y; v.y = B0.z; v.z = A0.w; v.w = A1.x;  o[1] = v;
    v.x = A1.y; v.y = B0.w; v.z = B1.x; v.w = B1.y;  o[2] = v;
    v.x = A1.z; v.y = A1.w; v.z = A2.x; v.w = B1.z;  o[3] = v;
    v.x = B1.w; v.y = B2.x; v.z = A2.y; v.w = A2.z;  o[4] = v;
    v.x = A2.w; v.y = B2.y; v.z = B2.z; v.w = B2.w;  o[5] = v;
}

extern "C" void kernel_launch(void* const* d_in, const int* in_sizes, int n_in,
                              void* d_out, int out_size, void* d_ws, size_t ws_size,
                              hipStream_t stream) {
    const float* reals = (const float*)d_in[0];
    const float* fakes = (const float*)d_in[1];
    const int*   idx   = (const int*)d_in[2];
    float* out = (float*)d_out;

    const int total_groups = BB * GRPS_PER_B;        // 1,048,576
    const int block = 256;
    const int grid = total_groups / block;           // 4096
    tochoices_kernel<<<grid, block, 0, stream>>>(reals, fakes, idx, out);
}

// Round 5
// 30.825 us; speedup vs baseline: 4.4666x; 1.3204x over previous
//
#include <hip/hip_runtime.h>

// ToChoices: out[b,h,w,s,c] = (shuffle_indices[b,s] ? reals : fakes)[b,h,w,c]
// reals/fakes (64,256,256,3) f32, shuffle_indices (64,2) int, out (64,256,256,2,3) f32.
//
// R4 lesson: the op is request-bound, not byte-bound (inputs L3-resident,
// FETCH ~36MB). Direct strided 16B/lane accesses (48-96B lane stride) cost
// 3-6x cache-line touches per wave instruction. Fix: LDS-stage a 1024-pixel
// tile so EVERY global load and store is lane-contiguous (lane i <-> base +
// i*16B, full 64-line bursts per wave op). The 12B-granularity interleave
// permutation is done via LDS scalar reads (stride-2 dwords ~ 2-way bank
// aliasing = free).  Cached stores only (R3: nontemporal = 4x regression).

typedef float f32x4 __attribute__((ext_vector_type(4)));

#define HW 65536                  // pixels per image
#define TILE_PIX 1024             // pixels per block-tile
#define TILES_PER_B (HW / TILE_PIX)   // 64
#define SRC_FLOATS (TILE_PIX * 3) // 3072 floats staged per source (12 KB)
#define OUT_FLOATS (TILE_PIX * 6) // 6144 floats out per tile (24 KB)

__global__ __launch_bounds__(256) void tochoices_kernel(
    const float* __restrict__ reals,
    const float* __restrict__ fakes,
    const int* __restrict__ idx,
    float* __restrict__ out)
{
    // A at lds+0, B at lds+3076 (pad of 4 floats keeps 16B alignment of B and
    // shifts its bank mapping by 4 to decorrelate A/B reads in phase 2).
    __shared__ __align__(16) float lds[SRC_FLOATS + 4 + SRC_FLOATS];
    float* ldsA = lds;
    float* ldsB = lds + SRC_FLOATS + 4;

    int blk  = blockIdx.x;
    int b    = blk >> 6;          // / TILES_PER_B
    int tile = blk & (TILES_PER_B - 1);
    int t    = threadIdx.x;

    int i0 = idx[b * 2 + 0];      // slot 0: 0 = fakes, 1 = reals
    int i1 = idx[b * 2 + 1];

    long inbase = (long)b * (HW * 3) + (long)tile * SRC_FLOATS;

    // ---- Phase 1: contiguous global -> LDS staging (3x float4 per thread) --
    const f32x4* pA = (const f32x4*)((i0 ? reals : fakes) + inbase);
    #pragma unroll
    for (int k = 0; k < 3; ++k)
        ((f32x4*)ldsA)[t + 256 * k] = pA[t + 256 * k];

    const float* B = ldsA;        // if both slots pick the same image, reuse A
    if (i1 != i0) {               // block-uniform branch
        const f32x4* pB = (const f32x4*)((i1 ? reals : fakes) + inbase);
        #pragma unroll
        for (int k = 0; k < 3; ++k)
            ((f32x4*)ldsB)[t + 256 * k] = pB[t + 256 * k];
        B = ldsB;
    }
    __syncthreads();

    // ---- Phase 2: permuted LDS reads -> contiguous global stores ----------
    // Tile-local out float4 index g; per pixel-pair h = g/3, r = g%3 the four
    // components come from (A = slot-0 source, B = slot-1 source, base 6h):
    //   r=0: A+0 A+1 A+2 B+0
    //   r=1: B+1 B+2 A+3 A+4
    //   r=2: A+5 B+3 B+4 B+5
    f32x4* o = (f32x4*)(out + (long)b * (HW * 6) + (long)tile * OUT_FLOATS);
    #pragma unroll
    for (int k = 0; k < 6; ++k) {
        int g = t + 256 * k;
        int h = g / 3;
        int r = g - 3 * h;        // g % 3
        const float* a6 = ldsA + 6 * h;
        const float* b6 = B    + 6 * h;

        const float* px = (r == 0) ? a6 + 0 : (r == 1) ? b6 + 1 : a6 + 5;
        const float* py = (r == 0) ? a6 + 1 : (r == 1) ? b6 + 2 : b6 + 3;
        const float* pz = (r == 0) ? a6 + 2 : (r == 1) ? a6 + 3 : b6 + 4;
        const float* pw = (r == 0) ? b6 + 0 : (r == 1) ? a6 + 4 : b6 + 5;

        f32x4 v;
        v.x = *px; v.y = *py; v.z = *pz; v.w = *pw;
        o[g] = v;                 // lane-contiguous 16B store
    }
}

extern "C" void kernel_launch(void* const* d_in, const int* in_sizes, int n_in,
                              void* d_out, int out_size, void* d_ws, size_t ws_size,
                              hipStream_t stream) {
    const float* reals = (const float*)d_in[0];
    const float* fakes = (const float*)d_in[1];
    const int*   idx   = (const int*)d_in[2];
    float* out = (float*)d_out;

    const int grid = 64 * TILES_PER_B;   // 4096 blocks, one 1024-pixel tile each
    tochoices_kernel<<<grid, 256, 0, stream>>>(reals, fakes, idx, out);
}